// Round 7
// baseline (29.566 us; speedup 1.0000x reference)
//
#include <hip/hip_runtime.h>

// AttnCutLoss: loss = -mean_b sum_j log(output[b,j]) * softmax_j(f1(labels[b,:j+1]) / tau)
// f1 at cutoff k (csum c, total t): 2c/(k+t), 0 if t==0.
// s_j in [0,~1.52] -> exp2 without max-subtract. ln(o) = ln2*log2(o).
//
// PIPELINED PERSISTENT WAVES: each wave processes RPW=4 consecutive rows with
// 1-row-deep prefetch. Steady state per row:
//   issue LB(next) ; vmcnt(16) -> scan(cur) ; issue OV(next) ; vmcnt(16) -> main(cur)
// All loads are volatile asm (ordered, un-sinkable); each waitcnt is followed by
// sched_barrier(0) (guide rule #18); buffers are statically named ping/pong (rule #20).

constexpr int L   = 2048;
constexpr int TPB = 256;                // 4 waves per block
constexpr int RPW = 4;                  // rows per wave
constexpr float TAU   = 0.95f;
constexpr float LOG2E = 1.4426950408889634f;
constexpr float LN2   = 0.6931471805599453f;

typedef float f32x4 __attribute__((ext_vector_type(4)));

#define ISSUE8(buf, p) do {                                                              \
    const f32x4* _p0 = (p);                                                              \
    const f32x4* _p4 = (p) + 256;                                                        \
    asm volatile("global_load_dwordx4 %0, %1, off"             : "=v"(buf[0]) : "v"(_p0)); \
    asm volatile("global_load_dwordx4 %0, %1, off offset:1024" : "=v"(buf[1]) : "v"(_p0)); \
    asm volatile("global_load_dwordx4 %0, %1, off offset:2048" : "=v"(buf[2]) : "v"(_p0)); \
    asm volatile("global_load_dwordx4 %0, %1, off offset:3072" : "=v"(buf[3]) : "v"(_p0)); \
    asm volatile("global_load_dwordx4 %0, %1, off"             : "=v"(buf[4]) : "v"(_p4)); \
    asm volatile("global_load_dwordx4 %0, %1, off offset:1024" : "=v"(buf[5]) : "v"(_p4)); \
    asm volatile("global_load_dwordx4 %0, %1, off offset:2048" : "=v"(buf[6]) : "v"(_p4)); \
    asm volatile("global_load_dwordx4 %0, %1, off offset:3072" : "=v"(buf[7]) : "v"(_p4)); \
} while (0)

#define WAITV(n) do { asm volatile("s_waitcnt vmcnt(" #n ")");                           \
                      __builtin_amdgcn_sched_barrier(0); } while (0)

struct SS {
    unsigned nibs;
    float total, K2;
    float T[8], E[8];
};

__device__ __forceinline__ SS do_scan(const f32x4 lb[8], int lane) {
    SS s;
    unsigned nibs = 0u;
#pragma unroll
    for (int c = 0; c < 8; ++c) {
        unsigned b = (unsigned)lb[c][0] | ((unsigned)lb[c][1] << 1)
                   | ((unsigned)lb[c][2] << 2) | ((unsigned)lb[c][3] << 3);
        nibs |= b << (4 * c);
    }
    unsigned w[4];
#pragma unroll
    for (int q = 0; q < 4; ++q) {
        unsigned c0 = __popc((nibs >> (8 * q)) & 0xFu);
        unsigned c1 = __popc((nibs >> (8 * q + 4)) & 0xFu);
        w[q] = c0 | (c1 << 16);
    }
#pragma unroll
    for (int d = 1; d < 64; d <<= 1) {
#pragma unroll
        for (int q = 0; q < 4; ++q) {
            unsigned n = __shfl_up(w[q], d, 64);
            if (lane >= d) w[q] += n;
        }
    }
#pragma unroll
    for (int q = 0; q < 4; ++q) {
        unsigned tw = __shfl(w[q], 63, 64);
        unsigned own0 = __popc((nibs >> (8 * q)) & 0xFu);
        unsigned own1 = __popc((nibs >> (8 * q + 4)) & 0xFu);
        s.T[2 * q]     = (float)(tw & 0xFFFFu);
        s.T[2 * q + 1] = (float)(tw >> 16);
        s.E[2 * q]     = (float)((w[q] & 0xFFFFu) - own0);
        s.E[2 * q + 1] = (float)((w[q] >> 16) - own1);
    }
    s.total = ((s.T[0] + s.T[1]) + (s.T[2] + s.T[3])) + ((s.T[4] + s.T[5]) + (s.T[6] + s.T[7]));
    s.K2    = (s.total > 0.f) ? (2.f * LOG2E / TAU) : 0.f;
    s.nibs  = nibs;
    return s;
}

__device__ __forceinline__ float do_main(const f32x4 ov[8], const SS& s, int lane) {
    float Z = 0.f, Wd = 0.f, off = 0.f;
#pragma unroll
    for (int c = 0; c < 8; ++c) {
        float cf = off + s.E[c];
        const unsigned nib = (s.nibs >> (4 * c)) & 0xFu;
        const float kb = s.total + (float)(c * 256 + 4 * lane);

        cf += (float)(nib & 1u);
        float e0 = __builtin_amdgcn_exp2f((s.K2 * cf) * __builtin_amdgcn_rcpf(kb + 1.f));
        Z += e0;  Wd = fmaf(__builtin_amdgcn_logf(ov[c][0]), e0, Wd);

        cf += (float)((nib >> 1) & 1u);
        float e1 = __builtin_amdgcn_exp2f((s.K2 * cf) * __builtin_amdgcn_rcpf(kb + 2.f));
        Z += e1;  Wd = fmaf(__builtin_amdgcn_logf(ov[c][1]), e1, Wd);

        cf += (float)((nib >> 2) & 1u);
        float e2 = __builtin_amdgcn_exp2f((s.K2 * cf) * __builtin_amdgcn_rcpf(kb + 3.f));
        Z += e2;  Wd = fmaf(__builtin_amdgcn_logf(ov[c][2]), e2, Wd);

        cf += (float)((nib >> 3) & 1u);
        float e3 = __builtin_amdgcn_exp2f((s.K2 * cf) * __builtin_amdgcn_rcpf(kb + 4.f));
        Z += e3;  Wd = fmaf(__builtin_amdgcn_logf(ov[c][3]), e3, Wd);

        off += s.T[c];
    }
#pragma unroll
    for (int d = 32; d; d >>= 1) {
        Z  += __shfl_xor(Z, d, 64);
        Wd += __shfl_xor(Wd, d, 64);
    }
    return -LN2 * Wd / Z;   // valid in lane 0
}

__global__ __launch_bounds__(TPB, 2) void attncut_row_kernel(
    const float* __restrict__ output,   // [B, L]
    const float* __restrict__ labels,   // [B, L]
    float* __restrict__ rowloss,        // [B]
    int B)
{
    const int wave = threadIdx.x >> 6;
    const int lane = threadIdx.x & 63;
    const int g    = blockIdx.x * 4 + wave;       // global wave id
    const int row0 = g * RPW;

    const f32x4* lp = reinterpret_cast<const f32x4*>(labels + (size_t)row0 * L) + lane;
    const f32x4* op = reinterpret_cast<const f32x4*>(output + (size_t)row0 * L) + lane;
    // row k base: +k*512 (f32x4 units)

    f32x4 Plb[8], Pov[8], Qlb[8], Qov[8];

    // ---- prologue: row0 labels + outputs in flight ----
    ISSUE8(Plb, lp);
    ISSUE8(Pov, op);

    // ===== row 0 (cur=P, next=Q) =====
    ISSUE8(Qlb, lp + 512);
    WAITV(16);                               // P.lb ready
    SS s0 = do_scan(Plb, lane);
    ISSUE8(Qov, op + 512);
    WAITV(16);                               // P.ov ready
    {
        float rl = do_main(Pov, s0, lane);
        if (lane == 0) rowloss[row0 + 0] = rl;
    }

    // ===== row 1 (cur=Q, next=P) =====
    ISSUE8(Plb, lp + 1024);
    WAITV(16);                               // Q.lb ready
    SS s1 = do_scan(Qlb, lane);
    ISSUE8(Pov, op + 1024);
    WAITV(16);                               // Q.ov ready
    {
        float rl = do_main(Qov, s1, lane);
        if (lane == 0) rowloss[row0 + 1] = rl;
    }

    // ===== row 2 (cur=P, next=Q) =====
    ISSUE8(Qlb, lp + 1536);
    WAITV(16);                               // P.lb ready
    SS s2 = do_scan(Plb, lane);
    ISSUE8(Qov, op + 1536);
    WAITV(16);                               // P.ov ready
    {
        float rl = do_main(Pov, s2, lane);
        if (lane == 0) rowloss[row0 + 2] = rl;
    }

    // ===== row 3 (cur=Q, no next) =====
    WAITV(8);                                // Q.lb ready (Q.ov still in flight)
    SS s3 = do_scan(Qlb, lane);
    WAITV(0);                                // Q.ov ready
    {
        float rl = do_main(Qov, s3, lane);
        if (lane == 0) rowloss[row0 + 3] = rl;
    }
}

__global__ __launch_bounds__(1024) void attncut_reduce_kernel(
    const float* __restrict__ rowloss, float* __restrict__ out, int B)
{
    const int t = threadIdx.x;
    const float4* r4 = reinterpret_cast<const float4*>(rowloss);
    float s = 0.f;
    for (int i = t; i < B / 4; i += 1024) {
        float4 v = r4[i];
        s += (v.x + v.y) + (v.z + v.w);
    }
#pragma unroll
    for (int d = 32; d; d >>= 1) s += __shfl_xor(s, d, 64);
    __shared__ float ws[16];
    if ((t & 63) == 0) ws[t >> 6] = s;
    __syncthreads();
    if (t < 16) {
        s = ws[t];
#pragma unroll
        for (int d = 8; d; d >>= 1) s += __shfl_xor(s, d, 64);
        if (t == 0) out[0] = s / (float)B;
    }
}

extern "C" void kernel_launch(void* const* d_in, const int* in_sizes, int n_in,
                              void* d_out, int out_size, void* d_ws, size_t ws_size,
                              hipStream_t stream) {
    const float* output = (const float*)d_in[0];   // [B, L, 1] fp32
    const float* labels = (const float*)d_in[1];   // [B, L]    fp32
    const int B = in_sizes[1] / L;                 // 8192

    float* rowloss = (float*)d_ws;                 // B floats = 32 KB scratch

    const int blocks = B / (4 * RPW);              // 512
    attncut_row_kernel<<<blocks, TPB, 0, stream>>>(output, labels, rowloss, B);
    attncut_reduce_kernel<<<1, 1024, 0, stream>>>(rowloss, (float*)d_out, B);
}